// Round 9
// baseline (1582.633 us; speedup 1.0000x reference)
//
#include <hip/hip_runtime.h>

// ---------------------------------------------------------------------------
// HopfieldPooling on MI355X (gfx950)
//   prep: Wk -> planar hi/lo bf16 | q0 = query@Wq^T | zero P accumulators
//   gemm: k = x@Wk^T (verified split-bf16 3-term main loop) ->
//         (1) khead packed pre-swizzled store (unchanged)
//         (2) FUSED Hopfield iter 0: fp32 scores vs q0, exp, partial
//             (sum e*k, sum e) atomicAdd'd into global P.  Saves one full
//             201 MB khead pass in attn.
//   attn3: iterations 1..2 only (2 khead passes). gll double-buffered
//         staging, wave-local rounds (verified). q1 built from P at start.
//   out = (q@Wv^T)@Wproj^T + b
//   Workspace: khead | Plsum | q0 | wkh | wkl ; qcur aliases wkh, out1
//   aliases wkl (phase-disjoint). Pacc lives in d_out (scratch until proj2).
// ---------------------------------------------------------------------------

typedef float  float4v  __attribute__((ext_vector_type(4)));
typedef short  short4v  __attribute__((ext_vector_type(4)));
typedef short  short8v  __attribute__((ext_vector_type(8)));
typedef unsigned int uint4v __attribute__((ext_vector_type(4)));
typedef short8v bf16x8;   // 8 bf16 = 4 VGPRs, MFMA A/B frag

__device__ __forceinline__ void splitbf(float v, unsigned int& hi, unsigned int& lo){
  unsigned int u = __float_as_uint(v);
  hi = u >> 16;
  float r = v - __uint_as_float(u & 0xffff0000u);
  lo = (__float_as_uint(r) + 0x8000u) >> 16;
}
__device__ __forceinline__ unsigned int packbf(float v){
  unsigned int u = __float_as_uint(v);
  float r = v - __uint_as_float(u & 0xffff0000u);
  return (u >> 16) | ((__float_as_uint(r) + 0x8000u) & 0xffff0000u);
}

// async 16B global -> LDS copy (lane l of the wave lands at lptr + l*16)
__device__ __forceinline__ void gll16(const unsigned int* g, unsigned int* l){
  __builtin_amdgcn_global_load_lds(
      (const __attribute__((address_space(1))) unsigned int*)g,
      (__attribute__((address_space(3))) unsigned int*)l, 16, 0, 0);
}

// ---------------------------------------------------------------------------
// prep: [0,576) Wk planarize; [576,624) q0; [624,1392) zero Pacc;
//       [1392,1404) zero Plsum.
// ---------------------------------------------------------------------------
__global__ __launch_bounds__(256)
void prep_kernel(const float* __restrict__ wk, unsigned short* __restrict__ dh,
                 unsigned short* __restrict__ dl,
                 const float* __restrict__ query, const float* __restrict__ wq,
                 float* __restrict__ q0,
                 float* __restrict__ pacc, float* __restrict__ plsum){
  const int bid = blockIdx.x;
  if(bid < 576){
    size_t idx = (size_t)bid*256 + threadIdx.x;
    float4v v = ((const float4v*)wk)[idx];
    short4v h4, l4;
    #pragma unroll
    for(int e=0;e<4;e++){
      unsigned int hh, ll;
      splitbf(v[e], hh, ll);
      h4[e] = (short)hh;
      l4[e] = (short)ll;
    }
    ((short4v*)dh)[idx] = h4;
    ((short4v*)dl)[idx] = l4;
  } else if(bid < 624){
    int idx = (bid - 576)*256 + threadIdx.x;   // 12288
    int l = idx / 768, c = idx - l*768;
    const float* qr = query + l*768;
    const float* wr = wq + (size_t)c*768;
    float s = 0.f;
    for(int j=0;j<768;j+=4){
      float4v a  = *(const float4v*)(qr+j);
      float4v w4 = *(const float4v*)(wr+j);
      s += a[0]*w4[0]+a[1]*w4[1]+a[2]*w4[2]+a[3]*w4[3];
    }
    q0[idx] = s;
  } else if(bid < 1392){
    pacc[(size_t)(bid - 624)*256 + threadIdx.x] = 0.f;
  } else {
    plsum[(bid - 1392)*256 + threadIdx.x] = 0.f;
  }
}

// ---------------------------------------------------------------------------
// k = x @ Wk^T (verified main loop) + khead store + FUSED iter-0 partials.
// ---------------------------------------------------------------------------
__global__ __launch_bounds__(256, 3)
void gemm_k_kernel(const float* __restrict__ x, const unsigned short* __restrict__ wh,
                   const unsigned short* __restrict__ wl, unsigned int* __restrict__ khead,
                   const float* __restrict__ q0g,
                   float* __restrict__ pacc, float* __restrict__ plsum){
  __shared__ unsigned short Ah[512*8], Al[512*8];   // 16 KB, chunk layout
  __shared__ float kt[32*128];                      // 16 KB, epilogue k-tile
  __shared__ float q0s[2*16*64];                    // 8 KB, scaled q0 (2 heads)
  __shared__ float ep[32*16*2];                     // 4 KB, e-matrix
  const int tid  = threadIdx.x;
  const int id   = blockIdx.x;          // 0..3071
  const int xcd  = id & 7, slot = id >> 3;
  const int bml  = slot / 6;            // 0..63
  const int bn   = slot - bml*6;        // 0..5
  const int bm   = xcd*64 + bml;        // 0..511
  const int wave = tid >> 6, lane = tid & 63, quad = lane >> 4, l16 = lane & 15;

  float4v acc[8][2];
  #pragma unroll
  for(int i=0;i<8;i++)
    #pragma unroll
    for(int j=0;j<2;j++) acc[i][j] = (float4v){0.f,0.f,0.f,0.f};

  const float* xA = x + (size_t)bm*128*768;
  const unsigned short* wbh = wh + (size_t)(bn*128 + wave*32 + l16)*768 + quad*8;
  const unsigned short* wbl = wl + (size_t)(bn*128 + wave*32 + l16)*768 + quad*8;

  const int row0 = tid >> 2, c8 = tid & 3;
  const int C0 = row0*4 + (c8 ^ ((row0 >> 2) & 3));   // stride-1 per quarter-wave
  const int C1 = C0 + 256;
  const float* g0 = xA + (size_t)row0*768 + c8*8;
  const float* g1 = g0 + (size_t)64*768;
  const int crd = l16*4 + (quad ^ ((l16 >> 2) & 3));

  float4v p00 = *(const float4v*)(g0);
  float4v p01 = *(const float4v*)(g0 + 4);
  float4v p10 = *(const float4v*)(g1);
  float4v p11 = *(const float4v*)(g1 + 4);

  for(int k0=0;k0<768;k0+=32){
    bf16x8 b_h[2], b_l[2];
    #pragma unroll
    for(int j=0;j<2;j++){
      b_h[j] = *(const bf16x8*)(wbh + (size_t)j*16*768 + k0);
      b_l[j] = *(const bf16x8*)(wbl + (size_t)j*16*768 + k0);
    }
    __syncthreads();
    {
      short8v hv, lv;
      #pragma unroll
      for(int e=0;e<4;e++){
        unsigned int hh, ll;
        splitbf(p00[e], hh, ll); hv[e]   = (short)hh; lv[e]   = (short)ll;
        splitbf(p01[e], hh, ll); hv[e+4] = (short)hh; lv[e+4] = (short)ll;
      }
      *(short8v*)(Ah + C0*8) = hv;
      *(short8v*)(Al + C0*8) = lv;
      #pragma unroll
      for(int e=0;e<4;e++){
        unsigned int hh, ll;
        splitbf(p10[e], hh, ll); hv[e]   = (short)hh; lv[e]   = (short)ll;
        splitbf(p11[e], hh, ll); hv[e+4] = (short)hh; lv[e+4] = (short)ll;
      }
      *(short8v*)(Ah + C1*8) = hv;
      *(short8v*)(Al + C1*8) = lv;
    }
    __syncthreads();

    if(k0 + 32 < 768){
      p00 = *(const float4v*)(g0 + k0 + 32);
      p01 = *(const float4v*)(g0 + k0 + 36);
      p10 = *(const float4v*)(g1 + k0 + 32);
      p11 = *(const float4v*)(g1 + k0 + 36);
    }

    #pragma unroll
    for(int i=0;i<8;i++){
      bf16x8 a_h = *(const bf16x8*)(Ah + (size_t)(i*64 + crd)*8);
      bf16x8 a_l = *(const bf16x8*)(Al + (size_t)(i*64 + crd)*8);
      #pragma unroll
      for(int j=0;j<2;j++){
        acc[i][j] = __builtin_amdgcn_mfma_f32_16x16x32_bf16(a_h, b_h[j], acc[i][j],0,0,0);
        acc[i][j] = __builtin_amdgcn_mfma_f32_16x16x32_bf16(a_l, b_h[j], acc[i][j],0,0,0);
        acc[i][j] = __builtin_amdgcn_mfma_f32_16x16x32_bf16(a_h, b_l[j], acc[i][j],0,0,0);
      }
    }
  }

  // ---- epilogue 1: khead packed store in attn staging order (unchanged) ----
  const int b     = bm >> 5;
  const int Cbase = bn*128 + wave*32;
  const int h     = Cbase >> 6;
  const int dbase = Cbase & 63;
  const int nn0   = (bm & 31)*128;
  unsigned int* kout = khead + (size_t)(b*12 + h)*262144;
  #pragma unroll
  for(int i=0;i<8;i++){
    #pragma unroll
    for(int r=0;r<4;r++){
      const int n   = nn0 + i*16 + quad*4 + r;
      const int row = n & 255, t = n >> 8;
      const int ph  = ((row & 7) << 2) ^ ((row & 8) << 1);
      unsigned int* kr = kout + (size_t)t*16384 + row*64;
      #pragma unroll
      for(int j=0;j<2;j++)
        kr[(dbase + j*16 + l16) ^ ph] = packbf(acc[i][j][r]);
    }
  }

  // ---- epilogue 2: fused Hopfield iteration 0 (fp32, this tile's 128 keys) ----
  {
    const int h0 = bn*2;
    for(int idx = tid; idx < 2048; idx += 256){
      const int hp = idx >> 10, l = (idx >> 6) & 15, d = idx & 63;
      q0s[idx] = q0g[l*768 + (h0 + hp)*64 + d] * 0.125f;
    }
    const int ho = tid >> 7, lo = (tid >> 3) & 15, d8 = tid & 7;
    float pr[8];
    #pragma unroll
    for(int e=0;e<8;e++) pr[e] = 0.f;
    float pl = 0.f;
    for(int g = 0; g < 4; ++g){
      __syncthreads();            // prev group's (b) done with kt
      #pragma unroll
      for(int ii = 0; ii < 2; ++ii){
        const int i = g*2 + ii;
        #pragma unroll
        for(int j = 0; j < 2; ++j)
          #pragma unroll
          for(int r = 0; r < 4; ++r)
            kt[(ii*16 + quad*4 + r)*128 + wave*32 + j*16 + l16] = acc[i][j][r];
      }
      __syncthreads();
      {   // (a) scores + exp for rows g*32..g*32+31
        const int n = tid & 31, lb = (tid >> 5) << 1;
        #pragma unroll
        for(int dl = 0; dl < 2; ++dl)
          #pragma unroll
          for(int hp = 0; hp < 2; ++hp){
            float s = 0.f;
            const float* qp = q0s + hp*1024 + (lb + dl)*64;
            const float* kp = kt + n*128 + hp*64;
            #pragma unroll
            for(int d = 0; d < 64; d += 4){
              float4v a  = *(const float4v*)(qp + d);
              float4v kk = *(const float4v*)(kp + d);
              s += a[0]*kk[0] + a[1]*kk[1] + a[2]*kk[2] + a[3]*kk[3];
            }
            ep[(n*16 + lb + dl)*2 + hp] = __expf(s);
          }
      }
      __syncthreads();
      {   // (b) accumulate partials over the 32 rows
        const float* kb = kt + ho*64 + d8*8;
        #pragma unroll
        for(int n = 0; n < 32; ++n){
          const float e = ep[(n*16 + lo)*2 + ho];
          pl += e;
          const float4v k0 = *(const float4v*)(kb + n*128);
          const float4v k1 = *(const float4v*)(kb + n*128 + 4);
          pr[0] += e*k0[0]; pr[1] += e*k0[1]; pr[2] += e*k0[2]; pr[3] += e*k0[3];
          pr[4] += e*k1[0]; pr[5] += e*k1[1]; pr[6] += e*k1[2]; pr[7] += e*k1[3];
        }
      }
    }
    float* pa = pacc + (size_t)(b*12 + h0 + ho)*1024 + lo*64 + d8*8;
    #pragma unroll
    for(int e=0;e<8;e++) atomicAdd(pa + e, pr[e]);
    if(d8 == 0) atomicAdd(plsum + (b*12 + h0 + ho)*16 + lo, pl);
  }
}

// ---------------------------------------------------------------------------
// attn3: iterations 1..2 (iter 0 fused into gemm). One block per (b,h),
// 512 thr = 8 waves. q1 built from P partials at start. gll double-buffered
// staging (2x64KB), issue-first + vmcnt(8); wave-local rounds (verified).
// ---------------------------------------------------------------------------
__global__ __launch_bounds__(512, 2)
void attn3_kernel(const unsigned int* __restrict__ khead,
                  const float* __restrict__ pacc, const float* __restrict__ plsum,
                  float* __restrict__ qcur){
  __shared__ unsigned int knd[2*16384];           // 128 KB: buf0 | buf1
  float* accf  = (float*)(knd + 16384);           // [8][1024] (in buf1)
  float* lredf = (float*)(knd + 16384) + 8192;    // [8][16]
  float* qtmp  = (float*)(knd + 16384) + 8320;    // [16][64]

  const int tid  = threadIdx.x;
  const int bh   = blockIdx.x;
  const int b    = bh / 12;
  const int h    = bh - b*12;
  const int wave = tid >> 6, lane = tid & 63, quad = lane >> 4, l16 = lane & 15;

  const unsigned int* kg = khead + (size_t)bh*262144;
  const unsigned int* kwv = kg + wave*2048 + lane*4;
  unsigned int* lwv = knd + wave*2048;

  const int rowA = wave*32 + ((l16 >> 2) << 3) + (l16 & 3);
  const int rowB = rowA + 4;
  const int phiA = ((l16 & 3) << 2) ^ (((l16 >> 2) & 1) << 4);
  const int phiB = phiA ^ 16;
  const int q1   = quad & 1;

  // prologue: issue tile 0 -> buf0 (latency hides under q1 build)
  #pragma unroll
  for(int g=0; g<8; ++g) gll16(kwv + g*256, lwv + g*256);

  // build q1 = pacc/(1+plsum) into qtmp (iter-0 result)
  #pragma unroll
  for(int k2 = 0; k2 < 2; ++k2){
    const int i = tid + k2*512;
    qtmp[i] = pacc[(size_t)bh*1024 + i] / (1.f + plsum[bh*16 + (i >> 6)]);
  }
  __syncthreads();

  for(int iter = 1; iter < 3; ++iter){
    const float* qrow = qtmp + l16*64;
    bf16x8 qh[2], ql[2];
    #pragma unroll
    for(int s = 0; s < 2; ++s){
      float4v v0 = *(const float4v*)(qrow + s*32 + quad*8);
      float4v v1 = *(const float4v*)(qrow + s*32 + quad*8 + 4);
      #pragma unroll
      for(int e = 0; e < 8; ++e){
        float v = (e < 4 ? v0[e] : v1[e-4]) * 0.125f;
        unsigned int hh, ll;
        splitbf(v, hh, ll);
        qh[s][e] = (short)hh;
        ql[s][e] = (short)ll;
      }
    }
    __syncthreads();   // all waves done reading qtmp before buf1 reuse

    float4v acc[4];
    #pragma unroll
    for(int j=0;j<4;j++) acc[j] = (float4v){0.f,0.f,0.f,0.f};
    float lsum = 0.f;

    for(int t = 0; t < 16; ++t){
      const unsigned int* kcur = knd + ((t & 1) << 14);

      if(!(iter == 2 && t == 15)){
        const int tn = (t + 1) & 15;
        const unsigned int* gsrc = kwv + (size_t)tn*16384;
        unsigned int* ldst = lwv + (((t + 1) & 1) << 14);
        #pragma unroll
        for(int g=0; g<8; ++g) gll16(gsrc + g*256, ldst + g*256);
        asm volatile("s_waitcnt vmcnt(8)" ::: "memory");
      } else {
        asm volatile("s_waitcnt vmcnt(0)" ::: "memory");
      }
      __builtin_amdgcn_sched_barrier(0);

      float4v s1 = (float4v){0.f,0.f,0.f,0.f};
      float4v s2 = (float4v){0.f,0.f,0.f,0.f};
      #pragma unroll
      for(int s = 0; s < 2; ++s){
        const int c0 = s*32 + quad*8;
        uint4v w0 = *(const uint4v*)(kcur + rowA*64 + ((c0    ) ^ phiA));
        uint4v w1 = *(const uint4v*)(kcur + rowA*64 + ((c0 + 4) ^ phiA));
        uint4v u0 = *(const uint4v*)(kcur + rowB*64 + ((c0    ) ^ phiB));
        uint4v u1 = *(const uint4v*)(kcur + rowB*64 + ((c0 + 4) ^ phiB));
        bf16x8 a1h, a1l, a2h, a2l;
        #pragma unroll
        for(int j = 0; j < 4; ++j){
          a1h[j]   = (short)(w0[j] & 0xffffu);  a1l[j]   = (short)(w0[j] >> 16);
          a1h[j+4] = (short)(w1[j] & 0xffffu);  a1l[j+4] = (short)(w1[j] >> 16);
          a2h[j]   = (short)(u0[j] & 0xffffu);  a2l[j]   = (short)(u0[j] >> 16);
          a2h[j+4] = (short)(u1[j] & 0xffffu);  a2l[j+4] = (short)(u1[j] >> 16);
        }
        s1 = __builtin_amdgcn_mfma_f32_16x16x32_bf16(a1h, qh[s], s1, 0,0,0);
        s1 = __builtin_amdgcn_mfma_f32_16x16x32_bf16(a1l, qh[s], s1, 0,0,0);
        s1 = __builtin_amdgcn_mfma_f32_16x16x32_bf16(a1h, ql[s], s1, 0,0,0);
        s2 = __builtin_amdgcn_mfma_f32_16x16x32_bf16(a2h, qh[s], s2, 0,0,0);
        s2 = __builtin_amdgcn_mfma_f32_16x16x32_bf16(a2l, qh[s], s2, 0,0,0);
        s2 = __builtin_amdgcn_mfma_f32_16x16x32_bf16(a2h, ql[s], s2, 0,0,0);
      }

      bf16x8 pa_h, pa_l;
      #pragma unroll
      for(int e = 0; e < 4; ++e){
        float v = __expf(s1[e]);
        lsum += v;
        unsigned int hh, ll;
        splitbf(v, hh, ll);
        pa_h[e] = (short)hh;
        pa_l[e] = (short)ll;
        float v2 = __expf(s2[e]);
        lsum += v2;
        splitbf(v2, hh, ll);
        pa_h[e+4] = (short)hh;
        pa_l[e+4] = (short)ll;
      }

      const int rb0 = wave*32 + quad*8;
      #pragma unroll
      for(int j = 0; j < 4; ++j){
        bf16x8 kbh, kbl;
        #pragma unroll
        for(int e = 0; e < 8; ++e){
          const int jx = ((e >> 2) ^ q1) & 1;
          unsigned int w = kcur[(rb0 + e)*64 + ((j ^ jx) << 4) + (l16 ^ ((e & 3) << 2))];
          kbh[e] = (short)(w & 0xffffu);
          kbl[e] = (short)(w >> 16);
        }
        acc[j] = __builtin_amdgcn_mfma_f32_16x16x32_bf16(pa_h, kbh, acc[j], 0,0,0);
        acc[j] = __builtin_amdgcn_mfma_f32_16x16x32_bf16(pa_l, kbh, acc[j], 0,0,0);
        acc[j] = __builtin_amdgcn_mfma_f32_16x16x32_bf16(pa_h, kbl, acc[j], 0,0,0);
      }
    } // rounds

    __syncthreads();
    lsum += __shfl_xor(lsum, 16);
    lsum += __shfl_xor(lsum, 32);
    if(quad == 0) lredf[wave*16 + l16] = lsum;
    #pragma unroll
    for(int j = 0; j < 4; ++j)
      #pragma unroll
      for(int r = 0; r < 4; ++r)
        accf[wave*1024 + (quad*4 + r)*64 + j*16 + l16] = acc[j][r];
    __syncthreads();
    #pragma unroll
    for(int k = 0; k < 2; ++k){
      const int i = tid + k*512;
      const int l = i >> 6, d = i & 63;
      float s = 0.f, lt = 1.f;
      #pragma unroll
      for(int w = 0; w < 8; ++w){ s += accf[w*1024 + i]; }
      #pragma unroll
      for(int w = 0; w < 8; ++w){ lt += lredf[w*16 + l]; }
      const float qv = s / lt;
      if(iter < 2) qtmp[i] = qv;
      else qcur[(size_t)(b*16 + l)*768 + h*64 + d] = qv;
    }
    __syncthreads();
  } // iterations
}

// ---------------------------------------------------------------------------
// out[r][c] = sum_j inp[r][j]*W[c][j] (+bias). 4 rows x 256 cols per block.
// ---------------------------------------------------------------------------
__global__ __launch_bounds__(256)
void proj_kernel(const float* __restrict__ inp, const float* __restrict__ w,
                 const float* __restrict__ bias, float* __restrict__ out){
  __shared__ float rows[4*768];
  const int r0 = blockIdx.x*4;
  const int c  = blockIdx.y*256 + threadIdx.x;
  for(int j = threadIdx.x; j < 4*768; j += 256) rows[j] = inp[(size_t)r0*768 + j];
  __syncthreads();
  const float* wr = w + (size_t)c*768;
  float a0=0.f, a1=0.f, a2=0.f, a3=0.f;
  for(int j=0;j<768;j+=4){
    float4v w4 = *(const float4v*)(wr+j);
    float4v r0v = *(const float4v*)(rows+j);
    float4v r1v = *(const float4v*)(rows+768+j);
    float4v r2v = *(const float4v*)(rows+1536+j);
    float4v r3v = *(const float4v*)(rows+2304+j);
    #pragma unroll
    for(int e=0;e<4;e++){
      a0 += r0v[e]*w4[e]; a1 += r1v[e]*w4[e];
      a2 += r2v[e]*w4[e]; a3 += r3v[e]*w4[e];
    }
  }
  const float bb = bias ? bias[c] : 0.f;
  out[(size_t)(r0+0)*768 + c] = a0 + bb;
  out[(size_t)(r0+1)*768 + c] = a1 + bb;
  out[(size_t)(r0+2)*768 + c] = a2 + bb;
  out[(size_t)(r0+3)*768 + c] = a3 + bb;
}

// ---------------------------------------------------------------------------
extern "C" void kernel_launch(void* const* d_in, const int* in_sizes, int n_in,
                              void* d_out, int out_size, void* d_ws, size_t ws_size,
                              hipStream_t stream){
  const float* x     = (const float*)d_in[0];   // [16,4096,768]
  const float* query = (const float*)d_in[1];   // [1,16,768]
  const float* Wq    = (const float*)d_in[2];   // [768,768]
  const float* Wk    = (const float*)d_in[3];
  const float* Wv    = (const float*)d_in[4];
  const float* Wproj = (const float*)d_in[5];
  const float* bproj = (const float*)d_in[6];   // [768]
  float* out = (float*)d_out;                   // [16,16,768] fp32

  char* ws = (char*)d_ws;
  unsigned int*   khead = (unsigned int*)(ws);             // 201326592 B
  float*          plsum = (float*)(ws + 201326592);        // 12288 B
  float*          q0    = (float*)(ws + 201338880);        // 49152 B
  unsigned short* wkh   = (unsigned short*)(ws + 201388032); // 1179648 B
  unsigned short* wkl   = (unsigned short*)(ws + 202567680); // 1179648 B
  // phase-disjoint aliases:
  float*          qcur  = (float*)(ws + 201388032);        // aliases wkh (dead after gemm)
  float*          out1  = (float*)(ws + 202567680);        // aliases wkl (dead after gemm)
  float*          pacc  = (float*)d_out;                   // 786432 B scratch until proj2

  prep_kernel<<<1404, 256, 0, stream>>>(Wk, wkh, wkl, query, Wq, q0, pacc, plsum);
  gemm_k_kernel<<<3072, 256, 0, stream>>>(x, wkh, wkl, khead, q0, pacc, plsum);

  attn3_kernel<<<192, 512, 0, stream>>>(khead, pacc, plsum, qcur);

  proj_kernel<<<dim3(64, 3), 256, 0, stream>>>(qcur, Wv, nullptr, out1);
  proj_kernel<<<dim3(64, 3), 256, 0, stream>>>(out1, Wproj, bproj, out);
}